// Round 9
// baseline (737571.582 us; speedup 1.0000x reference)
//
#include <hip/hip_runtime.h>
#include <hip/hip_bf16.h>

#define NEVT 32768
#define NBLK (NEVT / 8)

typedef _Float16 f16;
typedef _Float16 f16x2 __attribute__((ext_vector_type(2)));
typedef float Row128[128];

#ifndef __has_builtin
#define __has_builtin(x) 0
#endif

__device__ __forceinline__ float dot2f(f16x2 a, f16x2 b, float c) {
#if __has_builtin(__builtin_amdgcn_fdot2)
  return __builtin_amdgcn_fdot2(a, b, c, false);
#else
  return c + (float)a[0] * (float)b[0] + (float)a[1] * (float)b[1];
#endif
}

__device__ __forceinline__ float lrelu(float v) { return v >= 0.f ? v : 0.2f * v; }

__device__ __forceinline__ float sigmoidf(float x) {
  return 1.f / (1.f + __expf(-x));
}

__device__ __forceinline__ float tanh_f(float x) {
  float ax = fabsf(x);
  float e = __expf(-2.f * ax);
  float t = (1.f - e) / (1.f + e);
  return x >= 0.f ? t : -t;
}

// One residual block on an 8-row tile held in LDS. 128 threads, thread u owns
// output unit u. Two internal barriers.
__device__ __forceinline__ void res_block(Row128* xb, Row128* hb,
    const float* __restrict__ w1, const float* __restrict__ b1,
    const float* __restrict__ w2, const float* __restrict__ b2, int u) {
  float acc[8];
  float bb = b1[u];
  #pragma unroll
  for (int r = 0; r < 8; ++r) acc[r] = bb;
  #pragma unroll 4
  for (int k = 0; k < 128; ++k) {
    float w = w1[u * 128 + k];
    #pragma unroll
    for (int r = 0; r < 8; ++r) acc[r] += w * xb[r][k];
  }
  #pragma unroll
  for (int r = 0; r < 8; ++r) hb[r][u] = lrelu(acc[r]);
  __syncthreads();
  bb = b2[u];
  #pragma unroll
  for (int r = 0; r < 8; ++r) acc[r] = bb;
  #pragma unroll 4
  for (int k = 0; k < 128; ++k) {
    float w = w2[u * 128 + k];
    #pragma unroll
    for (int r = 0; r < 8; ++r) acc[r] += w * hb[r][k];
  }
  #pragma unroll
  for (int r = 0; r < 8; ++r) xb[r][u] = lrelu(xb[r][u] + acc[r]);
  __syncthreads();
}

// ---------------- Encoder stage 1 ----------------
__global__ __launch_bounds__(128) void enc1_kernel(
    const int* __restrict__ atom, const float* __restrict__ tvec,
    const float* __restrict__ mvec, const float* __restrict__ atom_emb,
    const float* __restrict__ mag_w, const float* __restrict__ mag_b,
    const float* __restrict__ pos_w, const float* __restrict__ pos_b,
    const float* __restrict__ reduce_w, const float* __restrict__ reduce_b,
    const float* __restrict__ net_w1, const float* __restrict__ net_b1,
    const float* __restrict__ net_w2, const float* __restrict__ net_b2,
    const float* __restrict__ final_w, const float* __restrict__ final_b,
    float* __restrict__ xf, float* __restrict__ pg) {
  const int u = threadIdx.x;
  const int r0 = blockIdx.x * 8;
  __shared__ float xin[8][384];
  __shared__ float xb[8][128];
  __shared__ float hb[8][128];
  #pragma unroll
  for (int r = 0; r < 8; ++r) {
    int row = r0 + r;
    xin[r][u] = atom_emb[atom[row] * 128 + u];
    xin[r][128 + u] = tvec[row] * pos_w[u] + pos_b[u];
    xin[r][256 + u] = mvec[row] * mag_w[u] + mag_b[u];
  }
  __syncthreads();
  float acc[8];
  float bb = reduce_b[u];
  #pragma unroll
  for (int r = 0; r < 8; ++r) acc[r] = bb;
  #pragma unroll 4
  for (int k = 0; k < 384; ++k) {
    float w = reduce_w[u * 384 + k];
    #pragma unroll
    for (int r = 0; r < 8; ++r) acc[r] += w * xin[r][k];
  }
  #pragma unroll
  for (int r = 0; r < 8; ++r) xb[r][u] = acc[r];
  __syncthreads();
  for (int blk = 0; blk < 4; ++blk)
    res_block(xb, hb, net_w1 + blk * 16384, net_b1 + blk * 128,
              net_w2 + blk * 16384, net_b2 + blk * 128, u);
  bb = final_b[u];
  #pragma unroll
  for (int r = 0; r < 8; ++r) acc[r] = bb;
  #pragma unroll 4
  for (int k = 0; k < 128; ++k) {
    float w = final_w[u * 128 + k];
    #pragma unroll
    for (int r = 0; r < 8; ++r) acc[r] += w * xb[r][k];
  }
  float s = 0.f;
  #pragma unroll
  for (int r = 0; r < 8; ++r) {
    xf[(r0 + r) * 128 + u] = acc[r];
    s += acc[r];
  }
  pg[blockIdx.x * 128 + u] = s;
}

// ---------------- Deterministic column reduction: sum m rows of [128] -------
__global__ __launch_bounds__(1024) void reduce_kernel(
    const float* __restrict__ src, int m, float* __restrict__ dst) {
  int u = threadIdx.x & 127, c = threadIdx.x >> 7;
  float s = 0.f;
  for (int i = c; i < m; i += 8) s += src[i * 128 + u];
  __shared__ float tmp[8][128];
  tmp[c][u] = s;
  __syncthreads();
  if (c == 0) {
    float t = 0.f;
    #pragma unroll
    for (int j = 0; j < 8; ++j) t += tmp[j][u];
    dst[u] = t;
  }
}

// ---------------- Encoder stage 2 ----------------
__global__ __launch_bounds__(128) void enc2_kernel(
    const float* __restrict__ xf, const float* __restrict__ g,
    const float* __restrict__ redg_w, const float* __restrict__ redg_b,
    const float* __restrict__ wg_w1, const float* __restrict__ wg_b1,
    const float* __restrict__ wg_w2, const float* __restrict__ wg_b2,
    const float* __restrict__ gfinal_w, const float* __restrict__ gfinal_b,
    float* __restrict__ pz) {
  const int u = threadIdx.x;
  const int r0 = blockIdx.x * 8;
  __shared__ float xin[8][256];
  __shared__ float xb[8][128];
  __shared__ float hb[8][128];
  #pragma unroll
  for (int r = 0; r < 8; ++r) {
    xin[r][u] = xf[(r0 + r) * 128 + u];
    xin[r][128 + u] = g[u];
  }
  __syncthreads();
  float acc[8];
  float bb = redg_b[u];
  #pragma unroll
  for (int r = 0; r < 8; ++r) acc[r] = bb;
  #pragma unroll 4
  for (int k = 0; k < 256; ++k) {
    float w = redg_w[u * 256 + k];
    #pragma unroll
    for (int r = 0; r < 8; ++r) acc[r] += w * xin[r][k];
  }
  #pragma unroll
  for (int r = 0; r < 8; ++r) xb[r][u] = acc[r];
  __syncthreads();
  for (int blk = 0; blk < 4; ++blk)
    res_block(xb, hb, wg_w1 + blk * 16384, wg_b1 + blk * 128,
              wg_w2 + blk * 16384, wg_b2 + blk * 128, u);
  bb = gfinal_b[u];
  #pragma unroll
  for (int r = 0; r < 8; ++r) acc[r] = bb;
  #pragma unroll 4
  for (int k = 0; k < 128; ++k) {
    float w = gfinal_w[u * 128 + k];
    #pragma unroll
    for (int r = 0; r < 8; ++r) acc[r] += w * xb[r][k];
  }
  float s = 0.f;
  #pragma unroll
  for (int r = 0; r < 8; ++r) s += acc[r];
  pz[blockIdx.x * 128 + u] = s;
}

// ---------------- Weight pre-conversion f32 -> f16 ----------------
__global__ __launch_bounds__(256) void wprep_kernel(
    const float* __restrict__ wih, const float* __restrict__ whh,
    f16* __restrict__ w16i, f16* __restrict__ w16h) {
  int idx = blockIdx.x * 256 + threadIdx.x;
  if (idx < 196608) {
    w16i[idx] = (f16)wih[idx];
    w16h[idx] = (f16)whh[idx];
  }
}

// ---------------- Sequential GRU decoder (single workgroup, 1024 threads) ---
// R12: software prefetch across RAW barriers. R11's informative null: cutting
// global bytes 768->640 KB (J1 via LDS) made the step SLOWER (7700->8150 cyc)
// -> the loop is NOT bandwidth-bound; it is segment-serialized. __syncthreads
// drains vmcnt(0) before every s_barrier, so all 8 segments/step pay the full
// L2 issue+latency ramp from zero. Fix (HK/m201-proven pattern): replace all
// loop barriers with {s_waitcnt lgkmcnt(0); raw s_barrier} - correct because
// cross-thread data (pgf, srcbuf) is LDS-only - and issue each phase's weight
// loads ONE SEGMENT EARLY into named float4 registers (A0..A7 / B0..B7).
// Loads then stay in flight across the gate segment; their latency hides
// under existing work. No asm anchors (R4-R7 lesson): buffers are ordinary
// short-lived values. Register budget: 64 prefetch + ~30 invariants (packed
// as 32-bit offsets) + transients < 128-cap at 4 waves/SIMD.
// Per-thread units J0..J5 and phase map (unchanged from baseline):
//   roleA (tid<512):  ph0:{J0,J1a} ph1:{J2}     ph2:{J3,J4a} ph3:{J5}
//   roleB (tid>=512): ph0:{J0}     ph1:{J1b,J2} ph2:{J3}     ph3:{J4b,J5}

#define BC(x) __builtin_bit_cast(f16x2, (x))

#define DGRPQ(WQ, Q) \
  a0_ = dot2f(BC((WQ).x), BC((Q).x), a0_); \
  a1_ = dot2f(BC((WQ).y), BC((Q).y), a1_); \
  a2_ = dot2f(BC((WQ).z), BC((Q).z), a2_); \
  a3_ = dot2f(BC((WQ).w), BC((Q).w), a3_);

// Dot a prefetched 8x-float4 register buffer against the LDS src slice.
#define UNIT_DOT_P(W, SOFF, DOFF, BIAS) do { \
  const float4* s4_ = (const float4*)(srcf + (SOFF)); \
  float4 q0_ = s4_[0], q1_ = s4_[1], q2_ = s4_[2], q3_ = s4_[3]; \
  float4 q4_ = s4_[4], q5_ = s4_[5], q6_ = s4_[6], q7_ = s4_[7]; \
  float a0_ = (BIAS), a1_ = 0.f, a2_ = 0.f, a3_ = 0.f; \
  DGRPQ(W##0, q0_) DGRPQ(W##1, q1_) DGRPQ(W##2, q2_) DGRPQ(W##3, q3_) \
  DGRPQ(W##4, q4_) DGRPQ(W##5, q5_) DGRPQ(W##6, q6_) DGRPQ(W##7, q7_) \
  pgf[(DOFF)] = (a0_ + a1_) + (a2_ + a3_); \
} while (0)

// Issue the 8 16-B loads for one unit into a named register buffer.
#define PF(P, OFF) do { \
  const float4* p_ = (const float4*)(w16 + (OFF)); \
  P##0 = p_[0]; P##1 = p_[1]; P##2 = p_[2]; P##3 = p_[3]; \
  P##4 = p_[4]; P##5 = p_[5]; P##6 = p_[6]; P##7 = p_[7]; \
} while (0)

// Raw barrier: LDS-drain only. Prefetch loads (vmcnt) stay in flight.
#define RAWBAR() do { \
  asm volatile("s_waitcnt lgkmcnt(0)" ::: "memory"); \
  __builtin_amdgcn_s_barrier(); \
} while (0)

// f32 peeled-step chunk: prefetched weight chunk vs f32 source.
#define F32CH(W4, XS, B) { f16x2 p_; \
  p_ = BC((W4).x); a0_ += (float)p_[0]*(XS)[(B)+0]; a1_ += (float)p_[1]*(XS)[(B)+1]; \
  p_ = BC((W4).y); a0_ += (float)p_[0]*(XS)[(B)+2]; a1_ += (float)p_[1]*(XS)[(B)+3]; \
  p_ = BC((W4).z); a0_ += (float)p_[0]*(XS)[(B)+4]; a1_ += (float)p_[1]*(XS)[(B)+5]; \
  p_ = BC((W4).w); a0_ += (float)p_[0]*(XS)[(B)+6]; a1_ += (float)p_[1]*(XS)[(B)+7]; }

// srcbuf (f16): [0,128)=cur, [128+l*128,...)=h16[l].
// pgf (float): [0,768)=gi partials (row*2+half), [768,1536)=gh.
// w16h sits contiguously at w16 + 196608 -> single 32-bit element offset.
#define SETUP_UNIT(J, JJ, P) \
  { int u_ = tid + (JJ)*1024; int lin_ = u_ / 1536; int w_ = u_ % 1536; \
    int layer_ = 2*(P) + lin_; int side_ = w_ / 768; int v_ = w_ % 768; \
    int row_ = v_ >> 1; int half_ = v_ & 1; \
    woff##J = side_ * 196608 + (layer_*384 + row_)*128 + half_*64; \
    soff##J = (side_ ? (1 + layer_) * 128 : 0) + half_ * 64; \
    doff##J = side_ * 768 + v_; \
    ubias##J = (half_ == 0) ? (side_ ? bhh : bih)[layer_*384 + row_] : 0.f; }

#define GATE(L, T) \
  if (tid < 128) { \
    const float2* gi2_ = (const float2*)pgf; \
    const float2* gh2_ = (const float2*)(pgf + 768); \
    float2 ar_ = gi2_[tid],      br_ = gh2_[tid]; \
    float2 az_ = gi2_[128+tid],  bz_ = gh2_[128+tid]; \
    float2 an_ = gi2_[256+tid],  bn_ = gh2_[256+tid]; \
    float r_ = sigmoidf((ar_.x + ar_.y) + (br_.x + br_.y)); \
    float z_ = sigmoidf((az_.x + az_.y) + (bz_.x + bz_.y)); \
    float n_ = tanh_f((an_.x + an_.y) + r_ * (bn_.x + bn_.y)); \
    float h_ = (1.f - z_) * n_ + z_ * h32[L][tid]; \
    h32[L][tid] = h_; f16 hh_ = (f16)h_; \
    srcbuf[(1 + (L)) * 128 + tid] = hh_; srcbuf[tid] = hh_; \
    if ((L) == 3) enc[(size_t)(T) * 128 + tid] = h_; \
  }

__global__ __attribute__((amdgpu_flat_work_group_size(1024, 1024)))
__attribute__((amdgpu_waves_per_eu(4, 4))) void gru_kernel(
    const f16* __restrict__ w16, const float* __restrict__ bih,
    const float* __restrict__ bhh, const float* __restrict__ zvec,
    float* __restrict__ enc) {
  const int tid = threadIdx.x;

  __shared__ __align__(16) float pgf[1536];
  __shared__ __align__(16) f16 srcbuf[640];
  __shared__ __align__(16) float h32[4][128];
  __shared__ __align__(16) float cur32[128];

  const f16* const srcf = srcbuf;

  int woff0, soff0, doff0; float ubias0;
  int woff1, soff1, doff1; float ubias1;
  int woff2, soff2, doff2; float ubias2;
  int woff3, soff3, doff3; float ubias3;
  int woff4, soff4, doff4; float ubias4;
  int woff5, soff5, doff5; float ubias5;

  SETUP_UNIT(0, 0, 0) SETUP_UNIT(1, 1, 0) SETUP_UNIT(2, 2, 0)
  SETUP_UNIT(3, 0, 1) SETUP_UNIT(4, 1, 1) SETUP_UNIT(5, 2, 1)

  float4 A0, A1, A2, A3, A4, A5, A6, A7;
  float4 B0, B1, B2, B3, B4, B5, B6, B7;

  if (tid < 128) {
    cur32[tid] = zvec[tid];
    srcbuf[tid] = (f16)0.f;
    #pragma unroll
    for (int l = 0; l < 4; ++l) {
      h32[l][tid] = 0.f;
      srcbuf[(1 + l) * 128 + tid] = (f16)0.f;
    }
  }
  __syncthreads();

  // ---- peeled step t = 0 (layer-0 gi uses f32 z; h == 0 elsewhere) ----
  {
    // ph0: in-phase loads (pipeline not yet primed)
    PF(A, woff0);
    if (tid < 512) PF(B, woff1);
    if (tid < 768) {  // J0 gi rows: f32 path (z ~1e7 overflows f16)
      const float* xs_ = cur32 + (tid & 1) * 64;
      float a0_ = ubias0, a1_ = 0.f;
      F32CH(A0, xs_, 0)  F32CH(A1, xs_, 8)  F32CH(A2, xs_, 16) F32CH(A3, xs_, 24)
      F32CH(A4, xs_, 32) F32CH(A5, xs_, 40) F32CH(A6, xs_, 48) F32CH(A7, xs_, 56)
      pgf[doff0] = a0_ + a1_;
    } else {
      UNIT_DOT_P(A, soff0, doff0, ubias0);
    }
    if (tid < 512) UNIT_DOT_P(B, soff1, doff1, ubias1);
    if (tid < 512) { PF(A, woff2); } else { PF(A, woff1); PF(B, woff2); }
    RAWBAR();
    GATE(0, 0)
    RAWBAR();
    // ph1
    if (tid < 512) {
      UNIT_DOT_P(A, soff2, doff2, ubias2);
    } else {
      UNIT_DOT_P(A, soff1, doff1, ubias1);
      UNIT_DOT_P(B, soff2, doff2, ubias2);
    }
    if (tid < 512) { PF(A, woff3); PF(B, woff4); } else { PF(A, woff3); }
    RAWBAR();
    GATE(1, 0)
    RAWBAR();
    // ph2
    UNIT_DOT_P(A, soff3, doff3, ubias3);
    if (tid < 512) UNIT_DOT_P(B, soff4, doff4, ubias4);
    if (tid < 512) { PF(A, woff5); } else { PF(A, woff4); PF(B, woff5); }
    RAWBAR();
    GATE(2, 0)
    RAWBAR();
    // ph3
    if (tid < 512) {
      UNIT_DOT_P(A, soff5, doff5, ubias5);
    } else {
      UNIT_DOT_P(A, soff4, doff4, ubias4);
      UNIT_DOT_P(B, soff5, doff5, ubias5);
    }
    if (tid < 512) { PF(A, woff0); PF(B, woff1); } else { PF(A, woff0); }
    RAWBAR();
    GATE(3, 0)
    RAWBAR();
  }

  #pragma unroll 1
  for (int t = 1; t < NEVT; ++t) {
    // ---- phase 0 (layer 0): A=J0 (all), B=J1a (tid<512) ----
    UNIT_DOT_P(A, soff0, doff0, ubias0);
    if (tid < 512) UNIT_DOT_P(B, soff1, doff1, ubias1);
    if (tid < 512) { PF(A, woff2); } else { PF(A, woff1); PF(B, woff2); }
    RAWBAR();
    GATE(0, t)
    RAWBAR();
    // ---- phase 1 (layer 1): roleA A=J2; roleB A=J1b, B=J2 ----
    if (tid < 512) {
      UNIT_DOT_P(A, soff2, doff2, ubias2);
    } else {
      UNIT_DOT_P(A, soff1, doff1, ubias1);
      UNIT_DOT_P(B, soff2, doff2, ubias2);
    }
    if (tid < 512) { PF(A, woff3); PF(B, woff4); } else { PF(A, woff3); }
    RAWBAR();
    GATE(1, t)
    RAWBAR();
    // ---- phase 2 (layer 2): A=J3 (all), B=J4a (tid<512) ----
    UNIT_DOT_P(A, soff3, doff3, ubias3);
    if (tid < 512) UNIT_DOT_P(B, soff4, doff4, ubias4);
    if (tid < 512) { PF(A, woff5); } else { PF(A, woff4); PF(B, woff5); }
    RAWBAR();
    GATE(2, t)
    RAWBAR();
    // ---- phase 3 (layer 3): roleA A=J5; roleB A=J4b, B=J5 ----
    if (tid < 512) {
      UNIT_DOT_P(A, soff5, doff5, ubias5);
    } else {
      UNIT_DOT_P(A, soff4, doff4, ubias4);
      UNIT_DOT_P(B, soff5, doff5, ubias5);
    }
    if (tid < 512) { PF(A, woff0); PF(B, woff1); } else { PF(A, woff0); }
    RAWBAR();
    GATE(3, t)
    RAWBAR();
  }
}

// ---------------- Output heads ----------------
__global__ __launch_bounds__(128) void heads_kernel(
    const float* __restrict__ enc,
    const float* __restrict__ ah_w1, const float* __restrict__ ah_b1,
    const float* __restrict__ ah_w2, const float* __restrict__ ah_b2,
    const float* __restrict__ ah_w, const float* __restrict__ ah_b,
    const float* __restrict__ ph_w1, const float* __restrict__ ph_b1,
    const float* __restrict__ ph_w2, const float* __restrict__ ph_b2,
    const float* __restrict__ ph_w, const float* __restrict__ ph_b,
    const float* __restrict__ mh_w1, const float* __restrict__ mh_b1,
    const float* __restrict__ mh_w2, const float* __restrict__ mh_b2,
    const float* __restrict__ mh_w, const float* __restrict__ mh_b,
    float* __restrict__ oa, float* __restrict__ op, float* __restrict__ om) {
  const int u = threadIdx.x;
  const int r0 = blockIdx.x * 8;
  __shared__ float eb[8][128], xb[8][128], hb[8][128];
  #pragma unroll
  for (int r = 0; r < 8; ++r) eb[r][u] = enc[(size_t)(r0 + r) * 128 + u];
  // ---- atoms head ----
  #pragma unroll
  for (int r = 0; r < 8; ++r) xb[r][u] = eb[r][u];
  __syncthreads();
  for (int blk = 0; blk < 2; ++blk)
    res_block(xb, hb, ah_w1 + blk * 16384, ah_b1 + blk * 128,
              ah_w2 + blk * 16384, ah_b2 + blk * 128, u);
  {
    float acc[8];
    float bb = ah_b[u];
    #pragma unroll
    for (int r = 0; r < 8; ++r) acc[r] = bb;
    #pragma unroll 4
    for (int k = 0; k < 128; ++k) {
      float w = ah_w[u * 128 + k];
      #pragma unroll
      for (int r = 0; r < 8; ++r) acc[r] += w * xb[r][k];
    }
    #pragma unroll
    for (int r = 0; r < 8; ++r) oa[(size_t)(r0 + r) * 128 + u] = acc[r];
  }
  __syncthreads();
  // ---- pos head ----
  #pragma unroll
  for (int r = 0; r < 8; ++r) xb[r][u] = eb[r][u];
  __syncthreads();
  for (int blk = 0; blk < 2; ++blk)
    res_block(xb, hb, ph_w1 + blk * 16384, ph_b1 + blk * 128,
              ph_w2 + blk * 16384, ph_b2 + blk * 128, u);
  if (u < 8) {
    int r = u;
    float s = ph_b[0];
    for (int k = 0; k < 128; ++k) s += ph_w[k] * xb[r][k];
    s = s < 0.f ? 0.f : (s > 1.f ? 1.f : s);
    op[r0 + r] = s;
  }
  __syncthreads();
  // ---- mags head ----
  #pragma unroll
  for (int r = 0; r < 8; ++r) xb[r][u] = eb[r][u];
  __syncthreads();
  for (int blk = 0; blk < 2; ++blk)
    res_block(xb, hb, mh_w1 + blk * 16384, mh_b1 + blk * 128,
              mh_w2 + blk * 16384, mh_b2 + blk * 128, u);
  if (u < 8) {
    int r = u;
    float s = mh_b[0];
    for (int k = 0; k < 128; ++k) s += mh_w[k] * xb[r][k];
    om[r0 + r] = s;
  }
}

extern "C" void kernel_launch(void* const* d_in, const int* in_sizes, int n_in,
                              void* d_out, int out_size, void* d_ws, size_t ws_size,
                              hipStream_t stream) {
  const int* atom = (const int*)d_in[0];
  const float* tvec = (const float*)d_in[1];
  const float* mvec = (const float*)d_in[2];
  const float* atom_emb = (const float*)d_in[3];
  const float* mag_w = (const float*)d_in[4];
  const float* mag_b = (const float*)d_in[5];
  const float* pos_w = (const float*)d_in[6];
  const float* pos_b = (const float*)d_in[7];
  const float* reduce_w = (const float*)d_in[8];
  const float* reduce_b = (const float*)d_in[9];
  const float* net_w1 = (const float*)d_in[10];
  const float* net_b1 = (const float*)d_in[11];
  const float* net_w2 = (const float*)d_in[12];
  const float* net_b2 = (const float*)d_in[13];
  const float* final_w = (const float*)d_in[14];
  const float* final_b = (const float*)d_in[15];
  const float* redg_w = (const float*)d_in[16];
  const float* redg_b = (const float*)d_in[17];
  const float* wg_w1 = (const float*)d_in[18];
  const float* wg_b1 = (const float*)d_in[19];
  const float* wg_w2 = (const float*)d_in[20];
  const float* wg_b2 = (const float*)d_in[21];
  const float* gfinal_w = (const float*)d_in[22];
  const float* gfinal_b = (const float*)d_in[23];
  const float* gru_wih = (const float*)d_in[24];
  const float* gru_whh = (const float*)d_in[25];
  const float* gru_bih = (const float*)d_in[26];
  const float* gru_bhh = (const float*)d_in[27];
  const float* ah_w1 = (const float*)d_in[28];
  const float* ah_b1 = (const float*)d_in[29];
  const float* ah_w2 = (const float*)d_in[30];
  const float* ah_b2 = (const float*)d_in[31];
  const float* ah_w = (const float*)d_in[32];
  const float* ah_b = (const float*)d_in[33];
  const float* ph_w1 = (const float*)d_in[34];
  const float* ph_b1 = (const float*)d_in[35];
  const float* ph_w2 = (const float*)d_in[36];
  const float* ph_b2 = (const float*)d_in[37];
  const float* ph_w = (const float*)d_in[38];
  const float* ph_b = (const float*)d_in[39];
  const float* mh_w1 = (const float*)d_in[40];
  const float* mh_b1 = (const float*)d_in[41];
  const float* mh_w2 = (const float*)d_in[42];
  const float* mh_b2 = (const float*)d_in[43];
  const float* mh_w = (const float*)d_in[44];
  const float* mh_b = (const float*)d_in[45];

  float* out = (float*)d_out;
  float* oa = out;                        // atoms [N,128]
  float* op = out + (size_t)NEVT * 128;   // pos [N]
  float* om = op + NEVT;                  // mags [N]
  float* oz = om + NEVT;                  // z [128]

  float* enc = (float*)d_ws;              // encodings [N,128] : 16 MB
  float* pg = enc + (size_t)NEVT * 128;   // stage-1 partials: 2 MB (reused for w16)
  float* pz = pg + (size_t)NBLK * 128;    // stage-2 partials: 2 MB
  float* gv = pz + (size_t)NBLK * 128;    // g [128]
  float* xf = oa;  // stage-1 output staged in atoms region; heads overwrite later

  // f16 weight copies overlay the pg region once pg has been reduced into gv.
  f16* w16i = (f16*)pg;                   // 384 KB
  f16* w16h = w16i + 196608;              // 384 KB (contiguous with w16i)

  enc1_kernel<<<NBLK, 128, 0, stream>>>(atom, tvec, mvec, atom_emb, mag_w, mag_b,
      pos_w, pos_b, reduce_w, reduce_b, net_w1, net_b1, net_w2, net_b2,
      final_w, final_b, xf, pg);
  reduce_kernel<<<1, 1024, 0, stream>>>(pg, NBLK, gv);
  wprep_kernel<<<768, 256, 0, stream>>>(gru_wih, gru_whh, w16i, w16h);
  enc2_kernel<<<NBLK, 128, 0, stream>>>(xf, gv, redg_w, redg_b, wg_w1, wg_b1,
      wg_w2, wg_b2, gfinal_w, gfinal_b, pz);
  reduce_kernel<<<1, 1024, 0, stream>>>(pz, NBLK, oz);
  gru_kernel<<<1, 1024, 0, stream>>>(w16i, gru_bih, gru_bhh, oz, enc);
  heads_kernel<<<NBLK, 128, 0, stream>>>(enc, ah_w1, ah_b1, ah_w2, ah_b2, ah_w, ah_b,
      ph_w1, ph_b1, ph_w2, ph_b2, ph_w, ph_b, mh_w1, mh_b1, mh_w2, mh_b2, mh_w, mh_b,
      oa, op, om);
}

// Round 10
// 109001.086 us; speedup vs baseline: 6.7666x; 6.7666x over previous
//
#include <hip/hip_runtime.h>
#include <hip/hip_bf16.h>

#define NEVT 32768
#define NBLK (NEVT / 8)

typedef _Float16 f16;
typedef _Float16 f16x2 __attribute__((ext_vector_type(2)));
typedef float f32x16 __attribute__((ext_vector_type(16)));
typedef float Row128[128];

#ifndef __has_builtin
#define __has_builtin(x) 0
#endif

__device__ __forceinline__ float dot2f(f16x2 a, f16x2 b, float c) {
#if __has_builtin(__builtin_amdgcn_fdot2)
  return __builtin_amdgcn_fdot2(a, b, c, false);
#else
  return c + (float)a[0] * (float)b[0] + (float)a[1] * (float)b[1];
#endif
}

__device__ __forceinline__ float lrelu(float v) { return v >= 0.f ? v : 0.2f * v; }

__device__ __forceinline__ float sigmoidf(float x) {
  return 1.f / (1.f + __expf(-x));
}

__device__ __forceinline__ float tanh_f(float x) {
  float ax = fabsf(x);
  float e = __expf(-2.f * ax);
  float t = (1.f - e) / (1.f + e);
  return x >= 0.f ? t : -t;
}

// One residual block on an 8-row tile held in LDS. 128 threads, thread u owns
// output unit u. Two internal barriers.
__device__ __forceinline__ void res_block(Row128* xb, Row128* hb,
    const float* __restrict__ w1, const float* __restrict__ b1,
    const float* __restrict__ w2, const float* __restrict__ b2, int u) {
  float acc[8];
  float bb = b1[u];
  #pragma unroll
  for (int r = 0; r < 8; ++r) acc[r] = bb;
  #pragma unroll 4
  for (int k = 0; k < 128; ++k) {
    float w = w1[u * 128 + k];
    #pragma unroll
    for (int r = 0; r < 8; ++r) acc[r] += w * xb[r][k];
  }
  #pragma unroll
  for (int r = 0; r < 8; ++r) hb[r][u] = lrelu(acc[r]);
  __syncthreads();
  bb = b2[u];
  #pragma unroll
  for (int r = 0; r < 8; ++r) acc[r] = bb;
  #pragma unroll 4
  for (int k = 0; k < 128; ++k) {
    float w = w2[u * 128 + k];
    #pragma unroll
    for (int r = 0; r < 8; ++r) acc[r] += w * hb[r][k];
  }
  #pragma unroll
  for (int r = 0; r < 8; ++r) xb[r][u] = lrelu(xb[r][u] + acc[r]);
  __syncthreads();
}

// ---------------- Encoder stage 1 ----------------
__global__ __launch_bounds__(128) void enc1_kernel(
    const int* __restrict__ atom, const float* __restrict__ tvec,
    const float* __restrict__ mvec, const float* __restrict__ atom_emb,
    const float* __restrict__ mag_w, const float* __restrict__ mag_b,
    const float* __restrict__ pos_w, const float* __restrict__ pos_b,
    const float* __restrict__ reduce_w, const float* __restrict__ reduce_b,
    const float* __restrict__ net_w1, const float* __restrict__ net_b1,
    const float* __restrict__ net_w2, const float* __restrict__ net_b2,
    const float* __restrict__ final_w, const float* __restrict__ final_b,
    float* __restrict__ xf, float* __restrict__ pg) {
  const int u = threadIdx.x;
  const int r0 = blockIdx.x * 8;
  __shared__ float xin[8][384];
  __shared__ float xb[8][128];
  __shared__ float hb[8][128];
  #pragma unroll
  for (int r = 0; r < 8; ++r) {
    int row = r0 + r;
    xin[r][u] = atom_emb[atom[row] * 128 + u];
    xin[r][128 + u] = tvec[row] * pos_w[u] + pos_b[u];
    xin[r][256 + u] = mvec[row] * mag_w[u] + mag_b[u];
  }
  __syncthreads();
  float acc[8];
  float bb = reduce_b[u];
  #pragma unroll
  for (int r = 0; r < 8; ++r) acc[r] = bb;
  #pragma unroll 4
  for (int k = 0; k < 384; ++k) {
    float w = reduce_w[u * 384 + k];
    #pragma unroll
    for (int r = 0; r < 8; ++r) acc[r] += w * xin[r][k];
  }
  #pragma unroll
  for (int r = 0; r < 8; ++r) xb[r][u] = acc[r];
  __syncthreads();
  for (int blk = 0; blk < 4; ++blk)
    res_block(xb, hb, net_w1 + blk * 16384, net_b1 + blk * 128,
              net_w2 + blk * 16384, net_b2 + blk * 128, u);
  bb = final_b[u];
  #pragma unroll
  for (int r = 0; r < 8; ++r) acc[r] = bb;
  #pragma unroll 4
  for (int k = 0; k < 128; ++k) {
    float w = final_w[u * 128 + k];
    #pragma unroll
    for (int r = 0; r < 8; ++r) acc[r] += w * xb[r][k];
  }
  float s = 0.f;
  #pragma unroll
  for (int r = 0; r < 8; ++r) {
    xf[(r0 + r) * 128 + u] = acc[r];
    s += acc[r];
  }
  pg[blockIdx.x * 128 + u] = s;
}

// ---------------- Deterministic column reduction: sum m rows of [128] -------
__global__ __launch_bounds__(1024) void reduce_kernel(
    const float* __restrict__ src, int m, float* __restrict__ dst) {
  int u = threadIdx.x & 127, c = threadIdx.x >> 7;
  float s = 0.f;
  for (int i = c; i < m; i += 8) s += src[i * 128 + u];
  __shared__ float tmp[8][128];
  tmp[c][u] = s;
  __syncthreads();
  if (c == 0) {
    float t = 0.f;
    #pragma unroll
    for (int j = 0; j < 8; ++j) t += tmp[j][u];
    dst[u] = t;
  }
}

// ---------------- Encoder stage 2 ----------------
__global__ __launch_bounds__(128) void enc2_kernel(
    const float* __restrict__ xf, const float* __restrict__ g,
    const float* __restrict__ redg_w, const float* __restrict__ redg_b,
    const float* __restrict__ wg_w1, const float* __restrict__ wg_b1,
    const float* __restrict__ wg_w2, const float* __restrict__ wg_b2,
    const float* __restrict__ gfinal_w, const float* __restrict__ gfinal_b,
    float* __restrict__ pz) {
  const int u = threadIdx.x;
  const int r0 = blockIdx.x * 8;
  __shared__ float xin[8][256];
  __shared__ float xb[8][128];
  __shared__ float hb[8][128];
  #pragma unroll
  for (int r = 0; r < 8; ++r) {
    xin[r][u] = xf[(r0 + r) * 128 + u];
    xin[r][128 + u] = g[u];
  }
  __syncthreads();
  float acc[8];
  float bb = redg_b[u];
  #pragma unroll
  for (int r = 0; r < 8; ++r) acc[r] = bb;
  #pragma unroll 4
  for (int k = 0; k < 256; ++k) {
    float w = redg_w[u * 256 + k];
    #pragma unroll
    for (int r = 0; r < 8; ++r) acc[r] += w * xin[r][k];
  }
  #pragma unroll
  for (int r = 0; r < 8; ++r) xb[r][u] = acc[r];
  __syncthreads();
  for (int blk = 0; blk < 4; ++blk)
    res_block(xb, hb, wg_w1 + blk * 16384, wg_b1 + blk * 128,
              wg_w2 + blk * 16384, wg_b2 + blk * 128, u);
  bb = gfinal_b[u];
  #pragma unroll
  for (int r = 0; r < 8; ++r) acc[r] = bb;
  #pragma unroll 4
  for (int k = 0; k < 128; ++k) {
    float w = gfinal_w[u * 128 + k];
    #pragma unroll
    for (int r = 0; r < 8; ++r) acc[r] += w * xb[r][k];
  }
  float s = 0.f;
  #pragma unroll
  for (int r = 0; r < 8; ++r) s += acc[r];
  pz[blockIdx.x * 128 + u] = s;
}

// ---------------- Weight pre-conversion f32 -> f16 ----------------
__global__ __launch_bounds__(256) void wprep_kernel(
    const float* __restrict__ wih, const float* __restrict__ whh,
    f16* __restrict__ w16i, f16* __restrict__ w16h) {
  int idx = blockIdx.x * 256 + threadIdx.x;
  if (idx < 196608) {
    w16i[idx] = (f16)wih[idx];
    w16h[idx] = (f16)whh[idx];
  }
}

// ---------------- Sequential GRU decoder (single workgroup, 1024 threads) ---
// FINAL (R13): baseline restored verbatim; declared at the per-CU memory
// roofline for a serial recurrence. Structural constraint, with the ledger:
//   - 32768 sequential steps x 786 KB weights/step; one CU's sustained
//     load-path rate ~100 B/cyc (measured across all passing configs)
//     -> ~7700 cyc/step -> ~105 ms. This kernel delivers exactly that.
//   - Residency is unobtainable: regs+LDS (~670 KB) < weights (768 KB);
//     the allocator spills any compiler-managed residency >~100 dw/lane
//     (R4/R5/R6/R12), physical AGPRs collide with compiler spill slots
//     (R7 NaN), class-"a" AGPRs cost ~+50% VALU in readbacks (R10).
//   - Fewer bytes loses: fp8 in-flight decode is VALU/latency-bound (R8).
//   - More CUs lose: only cross-CU wire is the coherence fabric,
//     ~500-900 cyc/hop x 4 serialized handoffs/step (R9: 23000 cyc/step).
//   - LDS weight feed loses: DS pipe shares issue/wait with the stream
//     (R11: -6%); cross-barrier register prefetch spills (R12: 7x).
// 6144 "units" (layer, gi/gh, row, half-of-128), 6 per thread. Phase l:
// 1536 active units x 32 v_dot2_f32_f16 -> LDS partials; 128 gate threads
// combine + sigmoid/tanh. Step 0 peeled: layer-0 gi in f32 (z ~1e7
// overflows f16).

#define PW(WV, K) __builtin_bit_cast(f16x2, (WV)[(K)])

#define DGRP(WV, G, Q) \
  a0_ = dot2f(PW(WV, 4*(G)+0), __builtin_bit_cast(f16x2, (Q).x), a0_); \
  a1_ = dot2f(PW(WV, 4*(G)+1), __builtin_bit_cast(f16x2, (Q).y), a1_); \
  a2_ = dot2f(PW(WV, 4*(G)+2), __builtin_bit_cast(f16x2, (Q).z), a2_); \
  a3_ = dot2f(PW(WV, 4*(G)+3), __builtin_bit_cast(f16x2, (Q).w), a3_);

#define UNIT_DOT(WA, WB, SRC, DST, BIAS) do { \
  const float4* s4_ = (const float4*)(SRC); \
  float4 q0_ = s4_[0], q1_ = s4_[1], q2_ = s4_[2], q3_ = s4_[3]; \
  float4 q4_ = s4_[4], q5_ = s4_[5], q6_ = s4_[6], q7_ = s4_[7]; \
  float a0_ = (BIAS), a1_ = 0.f, a2_ = 0.f, a3_ = 0.f; \
  DGRP(WA, 0, q0_) DGRP(WA, 1, q1_) DGRP(WA, 2, q2_) DGRP(WA, 3, q3_) \
  DGRP(WB, 0, q4_) DGRP(WB, 1, q5_) DGRP(WB, 2, q6_) DGRP(WB, 3, q7_) \
  *(DST) = (a0_ + a1_) + (a2_ + a3_); \
} while (0)

#define F32T(WV, K, XS, OFF) { f16x2 p_ = PW(WV, (K)); \
  a0_ += (float)p_[0] * (XS)[(OFF) + 2*(K)]; \
  a1_ += (float)p_[1] * (XS)[(OFF) + 2*(K) + 1]; }

#define UNIT_DOT_F32(WA, WB, XS, DST, BIAS) do { \
  float a0_ = (BIAS), a1_ = 0.f; \
  F32T(WA,0,XS,0) F32T(WA,1,XS,0) F32T(WA,2,XS,0) F32T(WA,3,XS,0) \
  F32T(WA,4,XS,0) F32T(WA,5,XS,0) F32T(WA,6,XS,0) F32T(WA,7,XS,0) \
  F32T(WA,8,XS,0) F32T(WA,9,XS,0) F32T(WA,10,XS,0) F32T(WA,11,XS,0) \
  F32T(WA,12,XS,0) F32T(WA,13,XS,0) F32T(WA,14,XS,0) F32T(WA,15,XS,0) \
  F32T(WB,0,XS,32) F32T(WB,1,XS,32) F32T(WB,2,XS,32) F32T(WB,3,XS,32) \
  F32T(WB,4,XS,32) F32T(WB,5,XS,32) F32T(WB,6,XS,32) F32T(WB,7,XS,32) \
  F32T(WB,8,XS,32) F32T(WB,9,XS,32) F32T(WB,10,XS,32) F32T(WB,11,XS,32) \
  F32T(WB,12,XS,32) F32T(WB,13,XS,32) F32T(WB,14,XS,32) F32T(WB,15,XS,32) \
  *(DST) = a0_ + a1_; \
} while (0)

#define L4(WV, I, Q) \
  (WV)[4*(I)+0] = (Q).x; (WV)[4*(I)+1] = (Q).y; \
  (WV)[4*(I)+2] = (Q).z; (WV)[4*(I)+3] = (Q).w;

#define LOAD_W16(WA, WB, BASE) do { \
  const float4* p_ = (const float4*)(BASE); \
  float4 q0_ = p_[0], q1_ = p_[1], q2_ = p_[2], q3_ = p_[3]; \
  float4 q4_ = p_[4], q5_ = p_[5], q6_ = p_[6], q7_ = p_[7]; \
  L4(WA, 0, q0_) L4(WA, 1, q1_) L4(WA, 2, q2_) L4(WA, 3, q3_) \
  L4(WB, 0, q4_) L4(WB, 1, q5_) L4(WB, 2, q6_) L4(WB, 3, q7_) \
} while (0)

#define SETUP_UNIT(J, JJ, P) \
  { int u_ = tid + (JJ)*1024; int lin_ = u_ / 1536; int w_ = u_ % 1536; \
    int layer_ = 2*(P) + lin_; int side_ = w_ / 768; int v_ = w_ % 768; \
    int row_ = v_ >> 1; int half_ = v_ & 1; \
    const f16* ws_ = side_ ? w16h : w16i; \
    const float* bs_ = side_ ? bhh : bih; \
    wb##J = ws_ + (size_t)(layer_*384 + row_)*128 + half_*64; \
    ubias##J = (half_ == 0) ? bs_[layer_*384 + row_] : 0.f; \
    usrc##J = (const f16x2*)(side_ ? &h16[layer_][0] : &cur16[0]) + half_*32; \
    udst##J = (side_ ? pgh : pgi) + v_; }

#define GATE(L, T) \
  if (tid < 128) { \
    const float2* gi2_ = (const float2*)pgi; const float2* gh2_ = (const float2*)pgh; \
    float2 ar_ = gi2_[tid],      br_ = gh2_[tid]; \
    float2 az_ = gi2_[128+tid],  bz_ = gh2_[128+tid]; \
    float2 an_ = gi2_[256+tid],  bn_ = gh2_[256+tid]; \
    float r_ = sigmoidf((ar_.x + ar_.y) + (br_.x + br_.y)); \
    float z_ = sigmoidf((az_.x + az_.y) + (bz_.x + bz_.y)); \
    float n_ = tanh_f((an_.x + an_.y) + r_ * (bn_.x + bn_.y)); \
    float h_ = (1.f - z_) * n_ + z_ * h32[L][tid]; \
    h32[L][tid] = h_; f16 hh_ = (f16)h_; \
    h16[L][tid] = hh_; cur16[tid] = hh_; \
    if ((L) == 3) enc[(size_t)(T) * 128 + tid] = h_; \
  }

__global__ __attribute__((amdgpu_flat_work_group_size(1024, 1024)))
__attribute__((amdgpu_waves_per_eu(4, 4))) void gru_kernel(
    const f16* __restrict__ w16i, const f16* __restrict__ w16h,
    const float* __restrict__ bih, const float* __restrict__ bhh,
    const float* __restrict__ zvec, float* __restrict__ enc) {
  const int tid = threadIdx.x;

  __shared__ __align__(16) float pgi[768];
  __shared__ __align__(16) float pgh[768];
  __shared__ __align__(16) f16 cur16[128];
  __shared__ __align__(16) f16 h16[4][128];
  __shared__ __align__(16) float h32[4][128];
  __shared__ __align__(16) float cur32[128];

  const f16* wb0; const f16x2* usrc0; float* udst0; float ubias0;
  const f16* wb1; const f16x2* usrc1; float* udst1; float ubias1;
  const f16* wb2; const f16x2* usrc2; float* udst2; float ubias2;
  const f16* wb3; const f16x2* usrc3; float* udst3; float ubias3;
  const f16* wb4; const f16x2* usrc4; float* udst4; float ubias4;
  const f16* wb5; const f16x2* usrc5; float* udst5; float ubias5;

  SETUP_UNIT(0, 0, 0) SETUP_UNIT(1, 1, 0) SETUP_UNIT(2, 2, 0)
  SETUP_UNIT(3, 0, 1) SETUP_UNIT(4, 1, 1) SETUP_UNIT(5, 2, 1)

  f32x16 w0a, w0b, w1a, w1b, w2a, w2b, w3a, w3b, w4a, w4b, w5a, w5b;
  LOAD_W16(w0a, w0b, wb0); LOAD_W16(w1a, w1b, wb1); LOAD_W16(w2a, w2b, wb2);
  LOAD_W16(w3a, w3b, wb3); LOAD_W16(w4a, w4b, wb4); LOAD_W16(w5a, w5b, wb5);

  if (tid < 128) {
    cur32[tid] = zvec[tid];
    cur16[tid] = (f16)0.f;
    #pragma unroll
    for (int l = 0; l < 4; ++l) { h32[l][tid] = 0.f; h16[l][tid] = (f16)0.f; }
  }
  __syncthreads();

  // ---- peeled step t = 0 (layer-0 gi uses f32 path; h == 0 elsewhere) ----
  {
    if (tid < 768) { UNIT_DOT_F32(w0a, w0b, cur32 + (tid & 1) * 64, udst0, ubias0); }
    else           { UNIT_DOT(w0a, w0b, usrc0, udst0, ubias0); }
    if (tid < 512) UNIT_DOT(w1a, w1b, usrc1, udst1, ubias1);
    __syncthreads();
    GATE(0, 0)
    __syncthreads();
    if (tid >= 512) UNIT_DOT(w1a, w1b, usrc1, udst1, ubias1);
    UNIT_DOT(w2a, w2b, usrc2, udst2, ubias2);
    __syncthreads();
    GATE(1, 0)
    __syncthreads();
    UNIT_DOT(w3a, w3b, usrc3, udst3, ubias3);
    if (tid < 512) UNIT_DOT(w4a, w4b, usrc4, udst4, ubias4);
    __syncthreads();
    GATE(2, 0)
    __syncthreads();
    if (tid >= 512) UNIT_DOT(w4a, w4b, usrc4, udst4, ubias4);
    UNIT_DOT(w5a, w5b, usrc5, udst5, ubias5);
    __syncthreads();
    GATE(3, 0)
    __syncthreads();
  }

  for (int t = 1; t < NEVT; ++t) {
    // ---- phase 0 (layer 0) ----
    UNIT_DOT(w0a, w0b, usrc0, udst0, ubias0);
    if (tid < 512) UNIT_DOT(w1a, w1b, usrc1, udst1, ubias1);
    __syncthreads();
    GATE(0, t)
    __syncthreads();
    // ---- phase 1 (layer 1) ----
    if (tid >= 512) UNIT_DOT(w1a, w1b, usrc1, udst1, ubias1);
    UNIT_DOT(w2a, w2b, usrc2, udst2, ubias2);
    __syncthreads();
    GATE(1, t)
    __syncthreads();
    // ---- phase 2 (layer 2) ----
    UNIT_DOT(w3a, w3b, usrc3, udst3, ubias3);
    if (tid < 512) UNIT_DOT(w4a, w4b, usrc4, udst4, ubias4);
    __syncthreads();
    GATE(2, t)
    __syncthreads();
    // ---- phase 3 (layer 3) ----
    if (tid >= 512) UNIT_DOT(w4a, w4b, usrc4, udst4, ubias4);
    UNIT_DOT(w5a, w5b, usrc5, udst5, ubias5);
    __syncthreads();
    GATE(3, t)
    __syncthreads();
  }
}

// ---------------- Output heads ----------------
__global__ __launch_bounds__(128) void heads_kernel(
    const float* __restrict__ enc,
    const float* __restrict__ ah_w1, const float* __restrict__ ah_b1,
    const float* __restrict__ ah_w2, const float* __restrict__ ah_b2,
    const float* __restrict__ ah_w, const float* __restrict__ ah_b,
    const float* __restrict__ ph_w1, const float* __restrict__ ph_b1,
    const float* __restrict__ ph_w2, const float* __restrict__ ph_b2,
    const float* __restrict__ ph_w, const float* __restrict__ ph_b,
    const float* __restrict__ mh_w1, const float* __restrict__ mh_b1,
    const float* __restrict__ mh_w2, const float* __restrict__ mh_b2,
    const float* __restrict__ mh_w, const float* __restrict__ mh_b,
    float* __restrict__ oa, float* __restrict__ op, float* __restrict__ om) {
  const int u = threadIdx.x;
  const int r0 = blockIdx.x * 8;
  __shared__ float eb[8][128], xb[8][128], hb[8][128];
  #pragma unroll
  for (int r = 0; r < 8; ++r) eb[r][u] = enc[(size_t)(r0 + r) * 128 + u];
  // ---- atoms head ----
  #pragma unroll
  for (int r = 0; r < 8; ++r) xb[r][u] = eb[r][u];
  __syncthreads();
  for (int blk = 0; blk < 2; ++blk)
    res_block(xb, hb, ah_w1 + blk * 16384, ah_b1 + blk * 128,
              ah_w2 + blk * 16384, ah_b2 + blk * 128, u);
  {
    float acc[8];
    float bb = ah_b[u];
    #pragma unroll
    for (int r = 0; r < 8; ++r) acc[r] = bb;
    #pragma unroll 4
    for (int k = 0; k < 128; ++k) {
      float w = ah_w[u * 128 + k];
      #pragma unroll
      for (int r = 0; r < 8; ++r) acc[r] += w * xb[r][k];
    }
    #pragma unroll
    for (int r = 0; r < 8; ++r) oa[(size_t)(r0 + r) * 128 + u] = acc[r];
  }
  __syncthreads();
  // ---- pos head ----
  #pragma unroll
  for (int r = 0; r < 8; ++r) xb[r][u] = eb[r][u];
  __syncthreads();
  for (int blk = 0; blk < 2; ++blk)
    res_block(xb, hb, ph_w1 + blk * 16384, ph_b1 + blk * 128,
              ph_w2 + blk * 16384, ph_b2 + blk * 128, u);
  if (u < 8) {
    int r = u;
    float s = ph_b[0];
    for (int k = 0; k < 128; ++k) s += ph_w[k] * xb[r][k];
    s = s < 0.f ? 0.f : (s > 1.f ? 1.f : s);
    op[r0 + r] = s;
  }
  __syncthreads();
  // ---- mags head ----
  #pragma unroll
  for (int r = 0; r < 8; ++r) xb[r][u] = eb[r][u];
  __syncthreads();
  for (int blk = 0; blk < 2; ++blk)
    res_block(xb, hb, mh_w1 + blk * 16384, mh_b1 + blk * 128,
              mh_w2 + blk * 16384, mh_b2 + blk * 128, u);
  if (u < 8) {
    int r = u;
    float s = mh_b[0];
    for (int k = 0; k < 128; ++k) s += mh_w[k] * xb[r][k];
    om[r0 + r] = s;
  }
}

extern "C" void kernel_launch(void* const* d_in, const int* in_sizes, int n_in,
                              void* d_out, int out_size, void* d_ws, size_t ws_size,
                              hipStream_t stream) {
  const int* atom = (const int*)d_in[0];
  const float* tvec = (const float*)d_in[1];
  const float* mvec = (const float*)d_in[2];
  const float* atom_emb = (const float*)d_in[3];
  const float* mag_w = (const float*)d_in[4];
  const float* mag_b = (const float*)d_in[5];
  const float* pos_w = (const float*)d_in[6];
  const float* pos_b = (const float*)d_in[7];
  const float* reduce_w = (const float*)d_in[8];
  const float* reduce_b = (const float*)d_in[9];
  const float* net_w1 = (const float*)d_in[10];
  const float* net_b1 = (const float*)d_in[11];
  const float* net_w2 = (const float*)d_in[12];
  const float* net_b2 = (const float*)d_in[13];
  const float* final_w = (const float*)d_in[14];
  const float* final_b = (const float*)d_in[15];
  const float* redg_w = (const float*)d_in[16];
  const float* redg_b = (const float*)d_in[17];
  const float* wg_w1 = (const float*)d_in[18];
  const float* wg_b1 = (const float*)d_in[19];
  const float* wg_w2 = (const float*)d_in[20];
  const float* wg_b2 = (const float*)d_in[21];
  const float* gfinal_w = (const float*)d_in[22];
  const float* gfinal_b = (const float*)d_in[23];
  const float* gru_wih = (const float*)d_in[24];
  const float* gru_whh = (const float*)d_in[25];
  const float* gru_bih = (const float*)d_in[26];
  const float* gru_bhh = (const float*)d_in[27];
  const float* ah_w1 = (const float*)d_in[28];
  const float* ah_b1 = (const float*)d_in[29];
  const float* ah_w2 = (const float*)d_in[30];
  const float* ah_b2 = (const float*)d_in[31];
  const float* ah_w = (const float*)d_in[32];
  const float* ah_b = (const float*)d_in[33];
  const float* ph_w1 = (const float*)d_in[34];
  const float* ph_b1 = (const float*)d_in[35];
  const float* ph_w2 = (const float*)d_in[36];
  const float* ph_b2 = (const float*)d_in[37];
  const float* ph_w = (const float*)d_in[38];
  const float* ph_b = (const float*)d_in[39];
  const float* mh_w1 = (const float*)d_in[40];
  const float* mh_b1 = (const float*)d_in[41];
  const float* mh_w2 = (const float*)d_in[42];
  const float* mh_b2 = (const float*)d_in[43];
  const float* mh_w = (const float*)d_in[44];
  const float* mh_b = (const float*)d_in[45];

  float* out = (float*)d_out;
  float* oa = out;                        // atoms [N,128]
  float* op = out + (size_t)NEVT * 128;   // pos [N]
  float* om = op + NEVT;                  // mags [N]
  float* oz = om + NEVT;                  // z [128]

  float* enc = (float*)d_ws;              // encodings [N,128] : 16 MB
  float* pg = enc + (size_t)NEVT * 128;   // stage-1 partials: 2 MB (reused for w16)
  float* pz = pg + (size_t)NBLK * 128;    // stage-2 partials: 2 MB
  float* gv = pz + (size_t)NBLK * 128;    // g [128]
  float* xf = oa;  // stage-1 output staged in atoms region; heads overwrite later

  // f16 weight copies overlay the pg region once pg has been reduced into gv.
  f16* w16i = (f16*)pg;                   // 384 KB
  f16* w16h = w16i + 196608;              // 384 KB

  enc1_kernel<<<NBLK, 128, 0, stream>>>(atom, tvec, mvec, atom_emb, mag_w, mag_b,
      pos_w, pos_b, reduce_w, reduce_b, net_w1, net_b1, net_w2, net_b2,
      final_w, final_b, xf, pg);
  reduce_kernel<<<1, 1024, 0, stream>>>(pg, NBLK, gv);
  wprep_kernel<<<768, 256, 0, stream>>>(gru_wih, gru_whh, w16i, w16h);
  enc2_kernel<<<NBLK, 128, 0, stream>>>(xf, gv, redg_w, redg_b, wg_w1, wg_b1,
      wg_w2, wg_b2, gfinal_w, gfinal_b, pz);
  reduce_kernel<<<1, 1024, 0, stream>>>(pz, NBLK, oz);
  gru_kernel<<<1, 1024, 0, stream>>>(w16i, w16h, gru_bih, gru_bhh, oz, enc);
  heads_kernel<<<NBLK, 128, 0, stream>>>(enc, ah_w1, ah_b1, ah_w2, ah_b2, ah_w, ah_b,
      ph_w1, ph_b1, ph_w2, ph_b2, ph_w, ph_b, mh_w1, mh_b1, mh_w2, mh_b2, mh_w, mh_b,
      oa, op, om);
}